// Round 11
// baseline (21.122 us; speedup 1.0000x reference)
//
#include <hip/hip_runtime.h>

#define NSTROKES 64
#define NSAMP    50
#define CANVAS   512
#define HW       (CANVAS * CANVAS)
#define TPB      1024                  // 512 px x 2 stroke-groups, 16 waves
#define SPW      (NSTROKES / 16)       // 4 strokes per wave (stage A)
#define LSTRIDE  64                    // float2 slots per stroke list
#define SOFFP    13                    // padded soff row (coprime w/ 32 banks)

// ---------------------------------------------------------------------------
// Single kernel, one block per canvas row. tid = px + 512*grp; grp g
// composites strokes g*32..g*32+31 (affine map c -> A*c + B), folded in LDS.
//  stage A: ballot compaction into per-stroke lists CSR-BUCKETED BY X
//           (8 x 64-px bins): 8 ballots + in-register prefix scan give each
//           kept sample its (bucket, rank) -> slot; offsets soff[s][0..8].
//           Lanes 50..63 append 14 sentinels after slot kc.
//  stage B: wave at x-span sg only touches buckets sg-1..sg+1 (contiguous
//           CSR range) of each stroke: a sample >13px away in x cannot move
//           alpha by more than sigmoid(-20). live = range non-empty (tighter
//           than any x-interval test). 2 strokes in flight per iteration.
// ---------------------------------------------------------------------------
__global__ __launch_bounds__(TPB, 8) void raster_fused_kernel(
    const float* __restrict__ strokes,   // (64,4,2)
    const float* __restrict__ widths,    // (64,)
    const float* __restrict__ colors,    // (64,3)
    float* __restrict__ out)             // (1,3,512,512)
{
    __shared__ __align__(16) float2 slist[NSTROKES * LSTRIDE];  // 32 KB
    __shared__ unsigned int soff[NSTROKES * SOFFP];             // CSR offsets
    __shared__ float4 scol[NSTROKES];    // r,g,b,w

    const int tid  = threadIdx.x;
    const int wave = tid >> 6;
    const int lane = tid & 63;
    const int px   = tid & 511;
    const int grp  = tid >> 9;           // 0: strokes 0-31, 1: strokes 32-63
    const int y    = blockIdx.x;
    const float fy = (float)y;

    // ---- stage A: compaction + x-bucketing, SPW strokes per wave
    #pragma unroll
    for (int i = 0; i < SPW; ++i) {
        const int s = wave * SPW + i;        // stroke id 0..63

        float4 a = ((const float4*)strokes)[s * 2];       // p0x,p0y,p1x,p1y
        float4 b = ((const float4*)strokes)[s * 2 + 1];   // p2x,p2y,p3x,p3y
        const float S = (float)CANVAS;
        float c0x = a.x * S;
        float c1x = 3.0f * (a.z - a.x) * S;
        float c2x = 3.0f * (b.x - 2.0f * a.z + a.x) * S;
        float c3x = (b.z - 3.0f * b.x + 3.0f * a.z - a.x) * S;
        float c0y = a.y * S;
        float c1y = 3.0f * (a.w - a.y) * S;
        float c2y = 3.0f * (b.y - 2.0f * a.w + a.y) * S;
        float c3y = (b.w - 3.0f * b.y + 3.0f * a.w - a.y) * S;

        float w   = widths[s];
        float cut = w + 10.0f;               // alpha <= sigmoid(-20) ~ 2e-9 beyond

        float t   = (float)lane * (1.0f / (float)(NSAMP - 1));
        float px_ = fmaf(fmaf(fmaf(c3x, t, c2x), t, c1x), t, c0x);
        float py_ = fmaf(fmaf(fmaf(c3y, t, c2y), t, c1y), t, c0y);

        bool keep = (lane < NSAMP) && (fabsf(py_ - fy) <= cut);

        int bkt = (int)px_ >> 6;             // curve in [0,512] by convex hull
        bkt = bkt < 0 ? 0 : (bkt > 7 ? 7 : bkt);

        // 8 ballots -> per-bucket masks; keep <=2 u64 live (VGPR pressure)
        unsigned long long mymask = 0ull;
        unsigned int cnts[8];
        #pragma unroll
        for (int bb = 0; bb < 8; ++bb) {
            unsigned long long mb = __ballot(keep && (bkt == bb));
            mymask = (bkt == bb) ? mb : mymask;
            cnts[bb] = (unsigned int)__popcll(mb);
        }
        unsigned int offs[9];
        offs[0] = 0;
        #pragma unroll
        for (int bb = 0; bb < 8; ++bb) offs[bb + 1] = offs[bb] + cnts[bb];
        const unsigned int kc = offs[8];

        unsigned int myoff = offs[0];
        #pragma unroll
        for (int bb = 1; bb < 8; ++bb) myoff = (bkt == bb) ? offs[bb] : myoff;
        int myidx = __popcll(mymask & ((1ull << lane) - 1ull));

        if (keep) {
            slist[s * LSTRIDE + myoff + myidx] = make_float2(px_, py_);
        } else if (lane >= NSAMP) {
            // 14 sentinels at kc..kc+13 cover the 4-wide loop's over-read
            slist[s * LSTRIDE + kc + (lane - NSAMP)] = make_float2(1e15f, 1e15f);
        }

        if (lane < 9) {                       // CSR offset table
            unsigned int v = offs[0];
            #pragma unroll
            for (int bb = 1; bb < 9; ++bb) v = (lane == bb) ? offs[bb] : v;
            soff[s * SOFFP + lane] = v;
        }
        if (lane == 0)
            scol[s] = make_float4(colors[3*s], colors[3*s+1], colors[3*s+2], w);
    }
    __syncthreads();

    // ---- stage B: per-span CSR windows; 2 strokes in flight
    const float fx  = (float)px;
    const int   sg  = wave & 7;                       // x-span of this wave
    const int   blo = sg > 0 ? sg - 1 : 0;            // first bucket
    const int   bhi = (sg < 7 ? sg + 1 : 7) + 1;      // exclusive-end entry
    const int   sbase = grp << 5;

    {   // alive = CSR range for buckets blo..bhi-1 non-empty
    }
    const int ls = sbase + (lane & 31);
    unsigned int st_l = soff[ls * SOFFP + blo];
    unsigned int en_l = soff[ls * SOFFP + bhi];
    unsigned int live = (unsigned int)__ballot(en_l > st_l);

    float A = 1.0f, br = 0.0f, bg = 0.0f, bb = 0.0f;

    while (live) {
        const int s0 = sbase + (__ffs(live) - 1);
        live &= live - 1u;
        const bool has1 = (live != 0u);
        const int s1 = has1 ? (sbase + (__ffs(live) - 1)) : s0;
        if (has1) live &= live - 1u;

        // independent LDS reads issue together (2x MLP)
        const int j0 = (int)(soff[s0 * SOFFP + blo] & ~3u);   // x4-aligned
        const int e0 = (int)soff[s0 * SOFFP + bhi];
        const int j1 = (int)(soff[s1 * SOFFP + blo] & ~3u);
        const int e1 = has1 ? (int)soff[s1 * SOFFP + bhi] : 0;
        float4 col0 = scol[s0];
        float4 col1 = scol[s1];
        const float w0 = col0.w, w1 = col1.w;

        float m0 = 1e30f, m1 = 1e30f;
        const float4* L0 = (const float4*)(slist + s0 * LSTRIDE);
        const float4* L1 = (const float4*)(slist + s1 * LSTRIDE);

        const int n0 = e0 - j0, n1 = e1 - j1;
        const int n  = n0 > n1 ? n0 : n1;
        for (int o = 0; o < n; o += 4) {              // sentinel-padded
            if (o < n0) {                             // wave-uniform branch
                float4 q0 = L0[(j0 + o) >> 1];
                float4 q1 = L0[((j0 + o) >> 1) + 1];
                float dy0 = fy - q0.y, dy1 = fy - q0.w;
                float dy2 = fy - q1.y, dy3 = fy - q1.w;
                float d0  = fx - q0.x, d1  = fx - q0.z;
                float d2  = fx - q1.x, d3  = fx - q1.z;
                float a01 = fminf(fmaf(d0, d0, dy0*dy0), fmaf(d1, d1, dy1*dy1));
                float a23 = fminf(fmaf(d2, d2, dy2*dy2), fmaf(d3, d3, dy3*dy3));
                m0 = fminf(fminf(a01, a23), m0);
            }
            if (o < n1) {
                float4 q0 = L1[(j1 + o) >> 1];
                float4 q1 = L1[((j1 + o) >> 1) + 1];
                float dy0 = fy - q0.y, dy1 = fy - q0.w;
                float dy2 = fy - q1.y, dy3 = fy - q1.w;
                float d0  = fx - q0.x, d1  = fx - q0.z;
                float d2  = fx - q1.x, d3  = fx - q1.z;
                float a01 = fminf(fmaf(d0, d0, dy0*dy0), fmaf(d1, d1, dy1*dy1));
                float a23 = fminf(fmaf(d2, d2, dy2*dy2), fmaf(d3, d3, dy3*dy3));
                m1 = fminf(fminf(a01, a23), m1);
            }
        }

        // both alphas with ILP; blend strictly s0 then s1 (composite order)
        float al0 = __builtin_amdgcn_rcpf(1.0f + __expf(2.0f * (sqrtf(m0) - w0)));
        float al1 = __builtin_amdgcn_rcpf(1.0f + __expf(2.0f * (sqrtf(m1) - w1)));

        A  *= (1.0f - al0);
        br  = fmaf(al0, col0.x - br, br);
        bg  = fmaf(al0, col0.y - bg, bg);
        bb  = fmaf(al0, col0.z - bb, bb);
        if (has1) {
            A  *= (1.0f - al1);
            br  = fmaf(al1, col1.x - br, br);
            bg  = fmaf(al1, col1.y - bg, bg);
            bb  = fmaf(al1, col1.z - bb, bb);
        }
    }

    // ---- combine: g0 publishes (A,B) via LDS (slist is dead), g1 folds
    __syncthreads();
    float4* xfer = (float4*)slist;           // 512 x float4 = 8 KB
    if (grp == 0) {
        xfer[px] = make_float4(A, br, bg, bb);
    }
    __syncthreads();
    if (grp == 1) {
        float4 g0 = xfer[px];
        // white canvas: c0 = A0*1 + B0; then c = A1*c0 + B1
        float cr = fmaf(A, g0.x + g0.y, br);
        float cg = fmaf(A, g0.x + g0.z, bg);
        float cb = fmaf(A, g0.x + g0.w, bb);
        const int base = y * CANVAS + px;
        out[0*HW + base] = cr;
        out[1*HW + base] = cg;
        out[2*HW + base] = cb;
    }
}

extern "C" void kernel_launch(void* const* d_in, const int* in_sizes, int n_in,
                              void* d_out, int out_size, void* d_ws, size_t ws_size,
                              hipStream_t stream) {
    const float* strokes = (const float*)d_in[0];
    const float* widths  = (const float*)d_in[1];
    const float* colors  = (const float*)d_in[2];
    float* out = (float*)d_out;

    raster_fused_kernel<<<dim3(CANVAS), dim3(TPB), 0, stream>>>(
        strokes, widths, colors, out);
}